// Round 5
// baseline (913.620 us; speedup 1.0000x reference)
//
#include <hip/hip_runtime.h>
#include <float.h>
#include <stdint.h>

// VectorQuantizer R5: pre-converted bf16 hi/lo + global_load_lds GEMM.
// R4 bottleneck (measured): vq_gemm VALUBusy 50% / MfmaUtil 29% — stage8
// conversion redundancy (emb 512x, inp 32x) + 8-way LDS write conflicts
// (SQ_LDS_BANK_CONFLICT 6.7e7). Fix: convert once (conv_split), stage via
// global_load_lds(16B) with source-octet swizzle for conflict-free ds_reads.
//
// Fast path (ws_size >= ~8MB):
//   d_out scratch: inp_hi bf16[16.7M] at +0, inp_lo at +32MB (=64MB exactly;
//     overwritten by vq_gather afterwards)
//   d_ws floats: esq[0,4096) | fcount 4097 | flags 4100.. | idx_final 69636..
//     | loss_part 135172.. | emb_hi @151556 | emb_lo @675844
//     | pmin2 @1200132 (4 slots/row) | pidx @1724420
// Fallback: R4 kernel set (stage8 in-GEMM), partials in d_out.

#define DDIM 256
#define KCODES 4096
#define NROWS 65536
#define QSIZE 16777216
#define NLBLK 16384
#define GAP_THRESH 0.02f

// fast-path ws float offsets
#define O_ESQ 0
#define O_FCOUNT 4097
#define O_FLAGS 4100
#define O_IDXF 69636
#define O_LPART 135172
#define O_EMBH 151556
#define O_EMBL 675844
#define O_PMIN2 1200132
#define O_PIDX 1724420
#define WS_FAST_BYTES ((size_t)1986564 * 4)

typedef short bf16x8 __attribute__((ext_vector_type(8)));
typedef float f32x4 __attribute__((ext_vector_type(4)));

__device__ __forceinline__ void gload_lds16(const void* g, void* l) {
    __builtin_amdgcn_global_load_lds(
        (const __attribute__((address_space(1))) void*)g,
        (__attribute__((address_space(3))) void*)l, 16, 0, 0);
}

// ---- esq + init: |e|^2 per code, zero flag counter ----
__global__ __launch_bounds__(64) void esq_kernel(const float* __restrict__ emb,
                                                 float* __restrict__ ws) {
    int c = blockIdx.x, l = threadIdx.x;
    const float4* e4 = (const float4*)(emb + (size_t)c * DDIM);
    float4 v = e4[l];
    float s = v.x * v.x + v.y * v.y + v.z * v.z + v.w * v.w;
#pragma unroll
    for (int off = 32; off >= 1; off >>= 1) s += __shfl_down(s, off);
    if (l == 0) ws[c] = s;
    if (c == 0 && l == 0) ((int*)ws)[O_FCOUNT] = 0;
}

// split fp32 -> (hi bf16 = RTZ top16, lo bf16 = RTZ(x - hi)); pack 8 elems
__device__ __forceinline__ void stage8(const float* __restrict__ p,
                                       short* __restrict__ dh,
                                       short* __restrict__ dl) {
    float4 a = *(const float4*)p;
    float4 b = *(const float4*)(p + 4);
    float f[8] = {a.x, a.y, a.z, a.w, b.x, b.y, b.z, b.w};
    uint32_t hu[8], lu[8];
#pragma unroll
    for (int k = 0; k < 8; ++k) {
        uint32_t u = __float_as_uint(f[k]);
        uint32_t h = u & 0xFFFF0000u;
        hu[k] = h;
        lu[k] = __float_as_uint(f[k] - __uint_as_float(h));
    }
    uint4 hv, lv;
    hv.x = __builtin_amdgcn_perm(hu[1], hu[0], 0x07060302u);
    hv.y = __builtin_amdgcn_perm(hu[3], hu[2], 0x07060302u);
    hv.z = __builtin_amdgcn_perm(hu[5], hu[4], 0x07060302u);
    hv.w = __builtin_amdgcn_perm(hu[7], hu[6], 0x07060302u);
    lv.x = __builtin_amdgcn_perm(lu[1], lu[0], 0x07060302u);
    lv.y = __builtin_amdgcn_perm(lu[3], lu[2], 0x07060302u);
    lv.z = __builtin_amdgcn_perm(lu[5], lu[4], 0x07060302u);
    lv.w = __builtin_amdgcn_perm(lu[7], lu[6], 0x07060302u);
    *(uint4*)dh = hv;
    *(uint4*)dl = lv;
}

// ---- one-time fp32 -> bf16 hi/lo conversion (memory-bound) ----
__global__ __launch_bounds__(256) void conv_split(const float* __restrict__ src,
                                                  short* __restrict__ dh,
                                                  short* __restrict__ dl, int n8) {
    int i = blockIdx.x * 256 + threadIdx.x;
    if (i < n8) stage8(src + (size_t)i * 8, dh + (size_t)i * 8, dl + (size_t)i * 8);
}

// ---- fast GEMM: 2048 blocks; 128 rows x 1024 codes; K'=768 via 3 bf16 passes ----
__global__ __launch_bounds__(256, 2) void vq_gemm_fast(
    const short* __restrict__ Ahg, const short* __restrict__ Alg,
    const short* __restrict__ Bhg, const short* __restrict__ Blg,
    const float* __restrict__ esq,
    float2* __restrict__ pmin2, int* __restrict__ pidx) {
    __shared__ __align__(16) short Ah[128 * 32];
    __shared__ __align__(16) short Al[128 * 32];
    __shared__ __align__(16) short Bh[128 * 32];
    __shared__ __align__(16) short Bl[128 * 32];
    __shared__ float sm1[2][128], sm2[2][128];
    __shared__ int sbi[2][128];

    const int t = threadIdx.x;
    const int mi = blockIdx.x >> 2, ng = blockIdx.x & 3;
    const size_t row0 = (size_t)mi * 128;
    const int lane = t & 63, wave = t >> 6;
    const int wm = wave >> 1, wn = wave & 1;
    const int n15 = lane & 15, quad = lane >> 4;
    const int swz = (n15 >> 1) & 3;  // read-side octet swizzle (matches store)

    float rm1[16], rm2[16];
    int rbi[16];
#pragma unroll
    for (int s = 0; s < 16; ++s) { rm1[s] = FLT_MAX; rm2[s] = FLT_MAX; rbi[s] = 0; }

    for (int ni = 0; ni < 8; ++ni) {
        const int colb = ng * 1024 + ni * 128;
        f32x4 acc[4][4];
#pragma unroll
        for (int i = 0; i < 4; ++i)
#pragma unroll
            for (int j = 0; j < 4; ++j) {
                acc[i][j][0] = 0.f; acc[i][j][1] = 0.f;
                acc[i][j][2] = 0.f; acc[i][j][3] = 0.f;
            }

        for (int ch = 0; ch < 8; ++ch) {
            __syncthreads();  // prior chunk's LDS reads complete
            // stage 4 tiles of 128x32 bf16 via global_load_lds (no VALU, no ds_write)
            // store layout: LDS[r][p] = SRC[r][p ^ ((r>>1)&3)]  (conflict-free reads)
#pragma unroll
            for (int k = 0; k < 2; ++k) {
                int e = t + k * 256;
                int r = e >> 2, p = e & 3;
                int kg = p ^ ((r >> 1) & 3);
                size_t asrc = (row0 + r) * DDIM + ch * 32 + kg * 8;
                size_t bsrc = (size_t)(colb + r) * DDIM + ch * 32 + kg * 8;
                gload_lds16(Ahg + asrc, &Ah[e * 8]);
                gload_lds16(Alg + asrc, &Al[e * 8]);
                gload_lds16(Bhg + bsrc, &Bh[e * 8]);
                gload_lds16(Blg + bsrc, &Bl[e * 8]);
            }
            __syncthreads();  // vmcnt(0) drained before barrier -> tiles visible

            bf16x8 ah[4], al[4];
#pragma unroll
            for (int i = 0; i < 4; ++i) {
                int off = (wm * 64 + i * 16 + n15) * 32 + ((quad ^ swz) * 8);
                ah[i] = *(const bf16x8*)&Ah[off];
                al[i] = *(const bf16x8*)&Al[off];
            }
#pragma unroll
            for (int j = 0; j < 4; ++j) {
                int boff = (wn * 64 + j * 16 + n15) * 32 + ((quad ^ swz) * 8);
                bf16x8 bh = *(const bf16x8*)&Bh[boff];
                bf16x8 bl = *(const bf16x8*)&Bl[boff];
#pragma unroll
                for (int i = 0; i < 4; ++i) {
                    acc[i][j] = __builtin_amdgcn_mfma_f32_16x16x32_bf16(ah[i], bh, acc[i][j], 0, 0, 0);
                    acc[i][j] = __builtin_amdgcn_mfma_f32_16x16x32_bf16(ah[i], bl, acc[i][j], 0, 0, 0);
                    acc[i][j] = __builtin_amdgcn_mfma_f32_16x16x32_bf16(al[i], bh, acc[i][j], 0, 0, 0);
                }
            }
        }

        // per-lane running top-2 over this ni's 128 codes (no shuffles here;
        // codes strictly increase across (ni,j) per lane -> numpy tie-break ok)
        float esqv[4];
#pragma unroll
        for (int j = 0; j < 4; ++j) esqv[j] = esq[colb + wn * 64 + j * 16 + n15];
#pragma unroll
        for (int i = 0; i < 4; ++i)
#pragma unroll
            for (int reg = 0; reg < 4; ++reg) {
                int s = i * 4 + reg;
#pragma unroll
                for (int j = 0; j < 4; ++j) {
                    float d = esqv[j] - 2.0f * acc[i][j][reg];
                    int code = colb + wn * 64 + j * 16 + n15;
                    if (d < rm1[s]) { rm2[s] = rm1[s]; rm1[s] = d; rbi[s] = code; }
                    else if (d < rm2[s]) rm2[s] = d;
                }
            }
    }

    // ---- final merge: 16 lanes -> LDS -> cross-wn -> 1 partial per (row, ng) ----
#pragma unroll
    for (int i = 0; i < 4; ++i)
#pragma unroll
        for (int reg = 0; reg < 4; ++reg) {
            int s = i * 4 + reg;
            float m1 = rm1[s], m2 = rm2[s];
            int bi = rbi[s];
#pragma unroll
            for (int off = 1; off < 16; off <<= 1) {
                float om1 = __shfl_xor(m1, off);
                float om2 = __shfl_xor(m2, off);
                int obi = __shfl_xor(bi, off);
                bool take = (om1 < m1) || (om1 == m1 && obi < bi);
                if (take) { m2 = fminf(m1, om2); m1 = om1; bi = obi; }
                else      { m2 = fminf(om1, m2); }
            }
            if (n15 == 0) {
                int rl = wm * 64 + i * 16 + quad * 4 + reg;
                sm1[wn][rl] = m1; sm2[wn][rl] = m2; sbi[wn][rl] = bi;
            }
        }
    __syncthreads();
    if (t < 128) {
        float m1 = sm1[0][t], m2 = sm2[0][t];
        int bi = sbi[0][t];
        float o1 = sm1[1][t], o2 = sm2[1][t];
        int ob = sbi[1][t];
        if (o1 < m1 || (o1 == m1 && ob < bi)) { m2 = fminf(m1, o2); m1 = o1; bi = ob; }
        else m2 = fminf(m2, o1);
        pmin2[(size_t)ng * NROWS + row0 + t] = make_float2(m1, m2);
        pidx[(size_t)ng * NROWS + row0 + t] = bi;
    }
}

// ---- R4 fallback GEMM (stage8 in-kernel, partials in d_out) ----
__global__ __launch_bounds__(256, 2) void vq_gemm_r4(const float* __restrict__ inp,
                                                     const float* __restrict__ emb,
                                                     const float* __restrict__ esq,
                                                     float2* __restrict__ pmin2,
                                                     int* __restrict__ pidx) {
    __shared__ __align__(16) short Ah[128 * 40];
    __shared__ __align__(16) short Al[128 * 40];
    __shared__ __align__(16) short Bh[128 * 40];
    __shared__ __align__(16) short Bl[128 * 40];

    const int t = threadIdx.x;
    const int mi = blockIdx.x >> 5, ni = blockIdx.x & 31;
    const size_t row0 = (size_t)mi * 128;
    const int col0 = ni * 128;
    const int lane = t & 63, wave = t >> 6;
    const int wm = wave >> 1, wn = wave & 1;
    const int n15 = lane & 15, quad = lane >> 4;

    f32x4 acc[4][4];
#pragma unroll
    for (int i = 0; i < 4; ++i)
#pragma unroll
        for (int j = 0; j < 4; ++j) {
            acc[i][j][0] = 0.f; acc[i][j][1] = 0.f;
            acc[i][j][2] = 0.f; acc[i][j][3] = 0.f;
        }

    for (int ch = 0; ch < 8; ++ch) {
        const int d0 = ch * 32;
        __syncthreads();
#pragma unroll
        for (int it = 0; it < 2; ++it) {
            int idx = t + 256 * it;
            int r = idx >> 2, c8 = idx & 3;
            stage8(inp + (row0 + r) * DDIM + d0 + 8 * c8,
                   &Ah[r * 40 + 8 * c8], &Al[r * 40 + 8 * c8]);
            stage8(emb + (size_t)(col0 + r) * DDIM + d0 + 8 * c8,
                   &Bh[r * 40 + 8 * c8], &Bl[r * 40 + 8 * c8]);
        }
        __syncthreads();

        bf16x8 ah[4], al[4], bh[4], bl[4];
#pragma unroll
        for (int i = 0; i < 4; ++i) {
            int off = (wm * 64 + i * 16 + n15) * 40 + quad * 8;
            ah[i] = *(const bf16x8*)&Ah[off];
            al[i] = *(const bf16x8*)&Al[off];
        }
#pragma unroll
        for (int j = 0; j < 4; ++j) {
            int off = (wn * 64 + j * 16 + n15) * 40 + quad * 8;
            bh[j] = *(const bf16x8*)&Bh[off];
            bl[j] = *(const bf16x8*)&Bl[off];
        }
#pragma unroll
        for (int i = 0; i < 4; ++i)
#pragma unroll
            for (int j = 0; j < 4; ++j) {
                acc[i][j] = __builtin_amdgcn_mfma_f32_16x16x32_bf16(ah[i], bh[j], acc[i][j], 0, 0, 0);
                acc[i][j] = __builtin_amdgcn_mfma_f32_16x16x32_bf16(ah[i], bl[j], acc[i][j], 0, 0, 0);
                acc[i][j] = __builtin_amdgcn_mfma_f32_16x16x32_bf16(al[i], bh[j], acc[i][j], 0, 0, 0);
            }
    }

    float esqv[4];
#pragma unroll
    for (int j = 0; j < 4; ++j) esqv[j] = esq[col0 + wn * 64 + j * 16 + n15];

#pragma unroll
    for (int i = 0; i < 4; ++i) {
#pragma unroll
        for (int reg = 0; reg < 4; ++reg) {
            float m1 = FLT_MAX, m2 = FLT_MAX;
            int bi = 0;
#pragma unroll
            for (int j = 0; j < 4; ++j) {
                float d = esqv[j] - 2.0f * acc[i][j][reg];
                int code = col0 + wn * 64 + j * 16 + n15;
                if (d < m1) { m2 = m1; m1 = d; bi = code; }
                else if (d < m2) { m2 = d; }
            }
#pragma unroll
            for (int off = 1; off < 16; off <<= 1) {
                float om1 = __shfl_xor(m1, off);
                float om2 = __shfl_xor(m2, off);
                int obi = __shfl_xor(bi, off);
                bool take = (om1 < m1) || (om1 == m1 && obi < bi);
                if (take) { m2 = fminf(m1, om2); m1 = om1; bi = obi; }
                else      { m2 = fminf(om1, m2); }
            }
            if (n15 == 0) {
                int rg = (int)row0 + wm * 64 + i * 16 + quad * 4 + reg;
                int slot = ni * 2 + wn;
                pmin2[(size_t)slot * NROWS + rg] = make_float2(m1, m2);
                pidx[(size_t)slot * NROWS + rg] = bi;
            }
        }
    }
}

// ---- reduce nslot partials per row; flag near-ties ----
__global__ __launch_bounds__(256) void vq_reduce(const float2* __restrict__ pmin2,
                                                 const int* __restrict__ pidx,
                                                 int* __restrict__ idx_final,
                                                 int* __restrict__ flags,
                                                 int* __restrict__ fcount, int nslot) {
    int row = blockIdx.x * 256 + threadIdx.x;
    float m1 = FLT_MAX, m2 = FLT_MAX;
    int bi = 0;
    for (int nb = 0; nb < nslot; ++nb) {
        float2 p = pmin2[(size_t)nb * NROWS + row];
        int pi = pidx[(size_t)nb * NROWS + row];
        if (p.x < m1) { m2 = fminf(m1, p.y); m1 = p.x; bi = pi; }
        else          { m2 = fminf(m2, p.x); }
    }
    idx_final[row] = bi;
    if (m2 - m1 < GAP_THRESH) {
        int s = atomicAdd(fcount, 1);
        flags[s] = row;
    }
}

// ---- fp32 recheck of flagged rows (exact R1 semantics) ----
__global__ __launch_bounds__(256) void vq_recheck(const float* __restrict__ inp,
                                                  const float* __restrict__ emb,
                                                  const float* __restrict__ esq,
                                                  const int* __restrict__ flags,
                                                  const int* __restrict__ fcount,
                                                  int* __restrict__ idx_final) {
    __shared__ float4 xs[64];
    __shared__ float sv[4];
    __shared__ int si[4];
    const int t = threadIdx.x;
    const int cnt = *fcount;
    for (int f = blockIdx.x; f < cnt; f += gridDim.x) {
        int row = flags[f];
        __syncthreads();
        if (t < 64) xs[t] = ((const float4*)inp)[(size_t)row * 64 + t];
        __syncthreads();
        float m1 = FLT_MAX;
        int bi = 0x7FFFFFFF;
        for (int cc = 0; cc < 16; ++cc) {
            int c = cc * 256 + t;
            const float4* e4 = (const float4*)emb + (size_t)c * 64;
            float dot = 0.f;
            for (int d4 = 0; d4 < 64; ++d4) {
                float4 e = e4[d4];
                float4 x = xs[d4];
                dot += e.x * x.x; dot += e.y * x.y;
                dot += e.z * x.z; dot += e.w * x.w;
            }
            float d = esq[c] - 2.0f * dot;
            if (d < m1 || (d == m1 && c < bi)) { m1 = d; bi = c; }
        }
#pragma unroll
        for (int off = 1; off < 64; off <<= 1) {
            float om = __shfl_xor(m1, off);
            int ob = __shfl_xor(bi, off);
            if (om < m1 || (om == m1 && ob < bi)) { m1 = om; bi = ob; }
        }
        if ((t & 63) == 0) { sv[t >> 6] = m1; si[t >> 6] = bi; }
        __syncthreads();
        if (t == 0) {
            for (int w = 1; w < 4; ++w)
                if (sv[w] < m1 || (sv[w] == m1 && si[w] < bi)) { m1 = sv[w]; bi = si[w]; }
            idx_final[row] = bi;
        }
    }
}

// ---- gather quantized, write indices, per-block loss partial ----
__global__ __launch_bounds__(256) void vq_gather(const float* __restrict__ inp,
                                                 const float* __restrict__ emb,
                                                 const int* __restrict__ idx_final,
                                                 float* __restrict__ out,
                                                 float* __restrict__ loss_part) {
    __shared__ float wsum[4];
    size_t gid = (size_t)blockIdx.x * 256 + threadIdx.x;
    int row = (int)(gid >> 6), c4 = (int)(gid & 63);
    int k = idx_final[row];
    float4 e = ((const float4*)emb)[(size_t)k * 64 + c4];
    float4 x = ((const float4*)inp)[gid];
    ((float4*)out)[gid] = e;
    float dx = e.x - x.x, dy = e.y - x.y, dz = e.z - x.z, dw = e.w - x.w;
    float ls = dx * dx + dy * dy + dz * dz + dw * dw;
#pragma unroll
    for (int off = 32; off >= 1; off >>= 1) ls += __shfl_down(ls, off);
    if ((threadIdx.x & 63) == 0) wsum[threadIdx.x >> 6] = ls;
    if (c4 == 0) out[(size_t)QSIZE + 1 + row] = (float)k;
    __syncthreads();
    if (threadIdx.x == 0)
        loss_part[blockIdx.x] = wsum[0] + wsum[1] + wsum[2] + wsum[3];
}

__global__ __launch_bounds__(256) void loss_kernel(const float* __restrict__ loss_part,
                                                   float* __restrict__ out) {
    __shared__ float sw[4];
    int t = threadIdx.x;
    float s = 0.0f;
    for (int i = t; i < NLBLK; i += 256) s += loss_part[i];
#pragma unroll
    for (int off = 32; off >= 1; off >>= 1) s += __shfl_down(s, off);
    if ((t & 63) == 0) sw[t >> 6] = s;
    __syncthreads();
    if (t == 0)
        out[QSIZE] = (sw[0] + sw[1] + sw[2] + sw[3]) * (1.0f / 16777216.0f);
}

extern "C" void kernel_launch(void* const* d_in, const int* in_sizes, int n_in,
                              void* d_out, int out_size, void* d_ws, size_t ws_size,
                              hipStream_t stream) {
    const float* inp = (const float*)d_in[0];
    const float* emb = (const float*)d_in[1];
    float* out = (float*)d_out;
    float* ws = (float*)d_ws;

    float* esq = ws + O_ESQ;
    int* fcount = (int*)ws + O_FCOUNT;
    int* flags = (int*)ws + O_FLAGS;
    int* idx_final = (int*)ws + O_IDXF;
    float* loss_part = ws + O_LPART;

    hipLaunchKernelGGL(esq_kernel, dim3(KCODES), dim3(64), 0, stream, emb, ws);

    if (ws_size >= WS_FAST_BYTES) {
        // ---- fast path ----
        short* ih = (short*)out;                    // inp_hi, 32MB
        short* il = (short*)(out + 8388608);        // inp_lo, 32MB
        short* eh = (short*)(ws + O_EMBH);
        short* el = (short*)(ws + O_EMBL);
        float2* pmin2 = (float2*)(ws + O_PMIN2);
        int* pidx = (int*)ws + O_PIDX;

        hipLaunchKernelGGL(conv_split, dim3(8192), dim3(256), 0, stream,
                           inp, ih, il, 2097152);
        hipLaunchKernelGGL(conv_split, dim3(512), dim3(256), 0, stream,
                           emb, eh, el, 131072);
        hipLaunchKernelGGL(vq_gemm_fast, dim3(2048), dim3(256), 0, stream,
                           ih, il, eh, el, esq, pmin2, pidx);
        hipLaunchKernelGGL(vq_reduce, dim3(NROWS / 256), dim3(256), 0, stream,
                           pmin2, pidx, idx_final, flags, fcount, 4);
    } else {
        // ---- R4 fallback: partials in d_out ----
        float2* pmin2 = (float2*)out;
        int* pidx = (int*)out + 8388608;
        hipLaunchKernelGGL(vq_gemm_r4, dim3((NROWS / 128) * 32), dim3(256), 0, stream,
                           inp, emb, esq, pmin2, pidx);
        hipLaunchKernelGGL(vq_reduce, dim3(NROWS / 256), dim3(256), 0, stream,
                           pmin2, pidx, idx_final, flags, fcount, 64);
    }

    hipLaunchKernelGGL(vq_recheck, dim3(256), dim3(256), 0, stream,
                       inp, emb, esq, flags, fcount, idx_final);
    hipLaunchKernelGGL(vq_gather, dim3(NLBLK), dim3(256), 0, stream,
                       inp, emb, idx_final, out, loss_part);
    hipLaunchKernelGGL(loss_kernel, dim3(1), dim3(256), 0, stream, loss_part, out);
}

// Round 6
// 836.450 us; speedup vs baseline: 1.0923x; 1.0923x over previous
//
#include <hip/hip_runtime.h>
#include <float.h>
#include <stdint.h>

// VectorQuantizer R6: R4 grid/epilogue (proven) + targeted staging fixes.
//  - emb pre-converted to bf16 hi/lo once (esq_conv, ws) -> B staged via
//    global_load_lds(16B), source-octet swizzle (R5-proven, 0 conflicts).
//  - inp converted in-kernel (A only, half of R4's staging VALU), ds_write
//    with dest-octet swizzle (same algebra as B: slot p holds octet p^s).
//  - addresses hoisted: unrolled ch loop folds ch*64B into offset imm.
//  - epilogue/merge/partials/reduce/recheck/gather: R4 verbatim (numerics
//    bit-identical to the passing R4 run).
// d_out = [quantized 16777216 f32][loss 1][indices 65536] ; scratch reuse:
//   pmin2 = 64 slots x float2 x 65536 rows (33.5MB), pidx 16.8MB -> 12.6M f
// d_ws floats: esq[0,4096) | fcount@4097 | flags@4100 | idx_final@69636 |
//   loss_part@135172 | emb_hi@151556 | emb_lo@675844  (total ~4.8 MB)

#define DDIM 256
#define KCODES 4096
#define NROWS 65536
#define QSIZE 16777216
#define NSLOT 64
#define NLBLK 16384
#define GAP_THRESH 0.02f

#define O_FCOUNT 4097
#define O_FLAGS 4100
#define O_IDXF 69636
#define O_LPART 135172
#define O_EMBH 151556
#define O_EMBL 675844

typedef short bf16x8 __attribute__((ext_vector_type(8)));
typedef float f32x4 __attribute__((ext_vector_type(4)));

__device__ __forceinline__ void gload_lds16(const void* g, void* l) {
    __builtin_amdgcn_global_load_lds(
        (const __attribute__((address_space(1))) void*)g,
        (__attribute__((address_space(3))) void*)l, 16, 0, 0);
}

// ---- esq + emb hi/lo conversion + init (one pass over emb) ----
__global__ __launch_bounds__(64) void esq_conv(const float* __restrict__ emb,
                                               float* __restrict__ ws,
                                               short* __restrict__ eh,
                                               short* __restrict__ el) {
    int c = blockIdx.x, l = threadIdx.x;
    const float4* e4 = (const float4*)(emb + (size_t)c * DDIM);
    float4 v = e4[l];
    float s = v.x * v.x + v.y * v.y + v.z * v.z + v.w * v.w;
    // convert 4 elems -> hi/lo bf16 (RTZ split, identical to stage8)
    float f[4] = {v.x, v.y, v.z, v.w};
    uint32_t hu[4], lu[4];
#pragma unroll
    for (int k = 0; k < 4; ++k) {
        uint32_t u = __float_as_uint(f[k]);
        uint32_t h = u & 0xFFFF0000u;
        hu[k] = h;
        lu[k] = __float_as_uint(f[k] - __uint_as_float(h));
    }
    uint2 hv, lv;
    hv.x = __builtin_amdgcn_perm(hu[1], hu[0], 0x07060302u);
    hv.y = __builtin_amdgcn_perm(hu[3], hu[2], 0x07060302u);
    lv.x = __builtin_amdgcn_perm(lu[1], lu[0], 0x07060302u);
    lv.y = __builtin_amdgcn_perm(lu[3], lu[2], 0x07060302u);
    *(uint2*)&eh[(size_t)c * DDIM + l * 4] = hv;
    *(uint2*)&el[(size_t)c * DDIM + l * 4] = lv;
#pragma unroll
    for (int off = 32; off >= 1; off >>= 1) s += __shfl_down(s, off);
    if (l == 0) ws[c] = s;
    if (c == 0 && l == 0) ((int*)ws)[O_FCOUNT] = 0;
}

// split fp32 -> (hi bf16, lo bf16), pack 8 elems, write 16B each to LDS
__device__ __forceinline__ void stage8(const float* __restrict__ p,
                                       short* __restrict__ dh,
                                       short* __restrict__ dl) {
    float4 a = *(const float4*)p;
    float4 b = *(const float4*)(p + 4);
    float f[8] = {a.x, a.y, a.z, a.w, b.x, b.y, b.z, b.w};
    uint32_t hu[8], lu[8];
#pragma unroll
    for (int k = 0; k < 8; ++k) {
        uint32_t u = __float_as_uint(f[k]);
        uint32_t h = u & 0xFFFF0000u;
        hu[k] = h;
        lu[k] = __float_as_uint(f[k] - __uint_as_float(h));
    }
    uint4 hv, lv;
    hv.x = __builtin_amdgcn_perm(hu[1], hu[0], 0x07060302u);
    hv.y = __builtin_amdgcn_perm(hu[3], hu[2], 0x07060302u);
    hv.z = __builtin_amdgcn_perm(hu[5], hu[4], 0x07060302u);
    hv.w = __builtin_amdgcn_perm(hu[7], hu[6], 0x07060302u);
    lv.x = __builtin_amdgcn_perm(lu[1], lu[0], 0x07060302u);
    lv.y = __builtin_amdgcn_perm(lu[3], lu[2], 0x07060302u);
    lv.z = __builtin_amdgcn_perm(lu[5], lu[4], 0x07060302u);
    lv.w = __builtin_amdgcn_perm(lu[7], lu[6], 0x07060302u);
    *(uint4*)dh = hv;
    *(uint4*)dl = lv;
}

// ---- main GEMM: 128x128 tile, 8 chunks of 32 dims, 3 bf16 passes ----
__global__ __launch_bounds__(256, 2) void vq_gemm(const float* __restrict__ inp,
                                                  const short* __restrict__ ehg,
                                                  const short* __restrict__ elg,
                                                  const float* __restrict__ esq,
                                                  float2* __restrict__ pmin2,
                                                  int* __restrict__ pidx) {
    __shared__ __align__(16) short Ah[128 * 32];  // 8 KB each, 32 KB total
    __shared__ __align__(16) short Al[128 * 32];
    __shared__ __align__(16) short Bh[128 * 32];
    __shared__ __align__(16) short Bl[128 * 32];

    const int t = threadIdx.x;
    const int mi = blockIdx.x >> 5, ni = blockIdx.x & 31;
    const size_t row0 = (size_t)mi * 128;
    const int col0 = ni * 128;
    const int lane = t & 63, wave = t >> 6;
    const int wm = wave >> 1, wn = wave & 1;
    const int n15 = lane & 15, quad = lane >> 4;
    const int swz = (n15 >> 1) & 3;

    // hoisted staging coords (granule = 8 elems)
    // A granules e0=t, e1=t+256: r=e>>2, c8=e&3; LDS slot p = c8 ^ ((r>>1)&3)
    const int ar0 = t >> 2, ac0 = t & 3;
    const int ap0 = ac0 ^ ((ar0 >> 1) & 3);
    const int ar1 = (t + 256) >> 2, ac1 = ac0;
    const int ap1 = ac1 ^ ((ar1 >> 1) & 3);
    const float* asrc0 = inp + (row0 + ar0) * DDIM + ac0 * 8;
    const float* asrc1 = inp + (row0 + ar1) * DDIM + ac1 * 8;
    short* adst0h = &Ah[ar0 * 32 + ap0 * 8];
    short* adst0l = &Al[ar0 * 32 + ap0 * 8];
    short* adst1h = &Ah[ar1 * 32 + ap1 * 8];
    short* adst1l = &Al[ar1 * 32 + ap1 * 8];
    // B granules: dest forced linear (lane*16); source octet swizzled
    const int br0 = ar0, bp0 = ac0, bk0 = bp0 ^ ((br0 >> 1) & 3);
    const int br1 = ar1, bp1 = ac1, bk1 = bp1 ^ ((br1 >> 1) & 3);
    const short* bsrc0h = ehg + (size_t)(col0 + br0) * DDIM + bk0 * 8;
    const short* bsrc0l = elg + (size_t)(col0 + br0) * DDIM + bk0 * 8;
    const short* bsrc1h = ehg + (size_t)(col0 + br1) * DDIM + bk1 * 8;
    const short* bsrc1l = elg + (size_t)(col0 + br1) * DDIM + bk1 * 8;

    f32x4 acc[4][4];
#pragma unroll
    for (int i = 0; i < 4; ++i)
#pragma unroll
        for (int j = 0; j < 4; ++j) {
            acc[i][j][0] = 0.f; acc[i][j][1] = 0.f;
            acc[i][j][2] = 0.f; acc[i][j][3] = 0.f;
        }

#pragma unroll
    for (int ch = 0; ch < 8; ++ch) {
        __syncthreads();  // prior chunk's LDS reads complete
        gload_lds16(bsrc0h + ch * 32, &Bh[t * 8]);
        gload_lds16(bsrc0l + ch * 32, &Bl[t * 8]);
        gload_lds16(bsrc1h + ch * 32, &Bh[(t + 256) * 8]);
        gload_lds16(bsrc1l + ch * 32, &Bl[(t + 256) * 8]);
        stage8(asrc0 + ch * 32, adst0h, adst0l);
        stage8(asrc1 + ch * 32, adst1h, adst1l);
        __syncthreads();  // drains vmcnt+lgkm -> tiles visible

        bf16x8 ah[4], al[4];
#pragma unroll
        for (int i = 0; i < 4; ++i) {
            int off = (wm * 64 + i * 16 + n15) * 32 + ((quad ^ swz) * 8);
            ah[i] = *(const bf16x8*)&Ah[off];
            al[i] = *(const bf16x8*)&Al[off];
        }
#pragma unroll
        for (int j = 0; j < 4; ++j) {
            int boff = (wn * 64 + j * 16 + n15) * 32 + ((quad ^ swz) * 8);
            bf16x8 bh = *(const bf16x8*)&Bh[boff];
            bf16x8 bl = *(const bf16x8*)&Bl[boff];
#pragma unroll
            for (int i = 0; i < 4; ++i) {
                acc[i][j] = __builtin_amdgcn_mfma_f32_16x16x32_bf16(ah[i], bh, acc[i][j], 0, 0, 0);
                acc[i][j] = __builtin_amdgcn_mfma_f32_16x16x32_bf16(ah[i], bl, acc[i][j], 0, 0, 0);
                acc[i][j] = __builtin_amdgcn_mfma_f32_16x16x32_bf16(al[i], bh, acc[i][j], 0, 0, 0);
            }
        }
    }

    // ---- epilogue: R4 verbatim (per-wave top-2 over its 64 codes) ----
    float esqv[4];
#pragma unroll
    for (int j = 0; j < 4; ++j) esqv[j] = esq[col0 + wn * 64 + j * 16 + n15];

#pragma unroll
    for (int i = 0; i < 4; ++i) {
#pragma unroll
        for (int reg = 0; reg < 4; ++reg) {
            float m1 = FLT_MAX, m2 = FLT_MAX;
            int bi = 0;
#pragma unroll
            for (int j = 0; j < 4; ++j) {
                float d = esqv[j] - 2.0f * acc[i][j][reg];
                int code = col0 + wn * 64 + j * 16 + n15;
                if (d < m1) { m2 = m1; m1 = d; bi = code; }
                else if (d < m2) { m2 = d; }
            }
#pragma unroll
            for (int off = 1; off < 16; off <<= 1) {
                float om1 = __shfl_xor(m1, off);
                float om2 = __shfl_xor(m2, off);
                int obi = __shfl_xor(bi, off);
                bool take = (om1 < m1) || (om1 == m1 && obi < bi);
                if (take) { m2 = fminf(m1, om2); m1 = om1; bi = obi; }
                else      { m2 = fminf(om1, m2); }
            }
            if (n15 == 0) {
                int rg = (int)row0 + wm * 64 + i * 16 + quad * 4 + reg;
                int slot = ni * 2 + wn;
                pmin2[(size_t)slot * NROWS + rg] = make_float2(m1, m2);
                pidx[(size_t)slot * NROWS + rg] = bi;
            }
        }
    }
}

// ---- reduce 64 per-wave partials per row; flag near-ties ----
__global__ __launch_bounds__(256) void vq_reduce(const float2* __restrict__ pmin2,
                                                 const int* __restrict__ pidx,
                                                 int* __restrict__ idx_final,
                                                 int* __restrict__ flags,
                                                 int* __restrict__ fcount) {
    int row = blockIdx.x * 256 + threadIdx.x;
    float m1 = FLT_MAX, m2 = FLT_MAX;
    int bi = 0;
    for (int nb = 0; nb < NSLOT; ++nb) {
        float2 p = pmin2[(size_t)nb * NROWS + row];
        int pi = pidx[(size_t)nb * NROWS + row];
        if (p.x < m1) { m2 = fminf(m1, p.y); m1 = p.x; bi = pi; }
        else          { m2 = fminf(m2, p.x); }
    }
    idx_final[row] = bi;
    if (m2 - m1 < GAP_THRESH) {
        int s = atomicAdd(fcount, 1);
        flags[s] = row;
    }
}

// ---- fp32 recheck of flagged rows (exact R1 semantics) ----
__global__ __launch_bounds__(256) void vq_recheck(const float* __restrict__ inp,
                                                  const float* __restrict__ emb,
                                                  const float* __restrict__ esq,
                                                  const int* __restrict__ flags,
                                                  const int* __restrict__ fcount,
                                                  int* __restrict__ idx_final) {
    __shared__ float4 xs[64];
    __shared__ float sv[4];
    __shared__ int si[4];
    const int t = threadIdx.x;
    const int cnt = *fcount;
    for (int f = blockIdx.x; f < cnt; f += gridDim.x) {
        int row = flags[f];
        __syncthreads();
        if (t < 64) xs[t] = ((const float4*)inp)[(size_t)row * 64 + t];
        __syncthreads();
        float m1 = FLT_MAX;
        int bi = 0x7FFFFFFF;
        for (int cc = 0; cc < 16; ++cc) {
            int c = cc * 256 + t;
            const float4* e4 = (const float4*)emb + (size_t)c * 64;
            float dot = 0.f;
            for (int d4 = 0; d4 < 64; ++d4) {
                float4 e = e4[d4];
                float4 x = xs[d4];
                dot += e.x * x.x; dot += e.y * x.y;
                dot += e.z * x.z; dot += e.w * x.w;
            }
            float d = esq[c] - 2.0f * dot;
            if (d < m1 || (d == m1 && c < bi)) { m1 = d; bi = c; }
        }
#pragma unroll
        for (int off = 1; off < 64; off <<= 1) {
            float om = __shfl_xor(m1, off);
            int ob = __shfl_xor(bi, off);
            if (om < m1 || (om == m1 && ob < bi)) { m1 = om; bi = ob; }
        }
        if ((t & 63) == 0) { sv[t >> 6] = m1; si[t >> 6] = bi; }
        __syncthreads();
        if (t == 0) {
            for (int w = 1; w < 4; ++w)
                if (sv[w] < m1 || (sv[w] == m1 && si[w] < bi)) { m1 = sv[w]; bi = si[w]; }
            idx_final[row] = bi;
        }
    }
}

// ---- gather quantized, write indices, per-block loss partial ----
__global__ __launch_bounds__(256) void vq_gather(const float* __restrict__ inp,
                                                 const float* __restrict__ emb,
                                                 const int* __restrict__ idx_final,
                                                 float* __restrict__ out,
                                                 float* __restrict__ loss_part) {
    __shared__ float wsum[4];
    size_t gid = (size_t)blockIdx.x * 256 + threadIdx.x;
    int row = (int)(gid >> 6), c4 = (int)(gid & 63);
    int k = idx_final[row];
    float4 e = ((const float4*)emb)[(size_t)k * 64 + c4];
    float4 x = ((const float4*)inp)[gid];
    ((float4*)out)[gid] = e;
    float dx = e.x - x.x, dy = e.y - x.y, dz = e.z - x.z, dw = e.w - x.w;
    float ls = dx * dx + dy * dy + dz * dz + dw * dw;
#pragma unroll
    for (int off = 32; off >= 1; off >>= 1) ls += __shfl_down(ls, off);
    if ((threadIdx.x & 63) == 0) wsum[threadIdx.x >> 6] = ls;
    if (c4 == 0) out[(size_t)QSIZE + 1 + row] = (float)k;
    __syncthreads();
    if (threadIdx.x == 0)
        loss_part[blockIdx.x] = wsum[0] + wsum[1] + wsum[2] + wsum[3];
}

__global__ __launch_bounds__(256) void loss_kernel(const float* __restrict__ loss_part,
                                                   float* __restrict__ out) {
    __shared__ float sw[4];
    int t = threadIdx.x;
    float s = 0.0f;
    for (int i = t; i < NLBLK; i += 256) s += loss_part[i];
#pragma unroll
    for (int off = 32; off >= 1; off >>= 1) s += __shfl_down(s, off);
    if ((t & 63) == 0) sw[t >> 6] = s;
    __syncthreads();
    if (t == 0)
        out[QSIZE] = (sw[0] + sw[1] + sw[2] + sw[3]) * (1.0f / 16777216.0f);
}

extern "C" void kernel_launch(void* const* d_in, const int* in_sizes, int n_in,
                              void* d_out, int out_size, void* d_ws, size_t ws_size,
                              hipStream_t stream) {
    const float* inp = (const float*)d_in[0];
    const float* emb = (const float*)d_in[1];
    float* out = (float*)d_out;
    float* ws = (float*)d_ws;

    float* esq = ws;
    int* fcount = (int*)ws + O_FCOUNT;
    int* flags = (int*)ws + O_FLAGS;
    int* idx_final = (int*)ws + O_IDXF;
    float* loss_part = ws + O_LPART;
    short* eh = (short*)(ws + O_EMBH);
    short* el = (short*)(ws + O_EMBL);

    // partials in d_out's quantized region (overwritten by vq_gather)
    float2* pmin2 = (float2*)out;                 // [0, 8388608) floats
    int* pidx = (int*)out + 8388608;              // [8388608, 12582912)

    hipLaunchKernelGGL(esq_conv, dim3(KCODES), dim3(64), 0, stream, emb, ws, eh, el);
    hipLaunchKernelGGL(vq_gemm, dim3((NROWS / 128) * 32), dim3(256), 0, stream,
                       inp, eh, el, esq, pmin2, pidx);
    hipLaunchKernelGGL(vq_reduce, dim3(NROWS / 256), dim3(256), 0, stream,
                       pmin2, pidx, idx_final, flags, fcount);
    hipLaunchKernelGGL(vq_recheck, dim3(256), dim3(256), 0, stream,
                       inp, emb, esq, flags, fcount, idx_final);
    hipLaunchKernelGGL(vq_gather, dim3(NLBLK), dim3(256), 0, stream,
                       inp, emb, idx_final, out, loss_part);
    hipLaunchKernelGGL(loss_kernel, dim3(1), dim3(256), 0, stream, loss_part, out);
}